// Round 9
// baseline (111.463 us; speedup 1.0000x reference)
//
#include <hip/hip_runtime.h>
#include <stdint.h>

#define IN_F   4096
#define OUT_F  768
#define NB     8
#define BATCH  4096
#define WCOLS  (OUT_F*NB)   // 6144
#define PREDN  (BATCH*OUT_F) // 3145728

typedef short  bf16x8  __attribute__((ext_vector_type(8)));
typedef float  f32x4   __attribute__((ext_vector_type(4)));
typedef unsigned short ushort8 __attribute__((ext_vector_type(8)));

__device__ __forceinline__ unsigned short f2bf(float f){
    union { float f; uint32_t u; } v; v.f = f;
    uint32_t u = v.u;
    u += 0x7FFFu + ((u >> 16) & 1u);   // round-to-nearest-even
    return (unsigned short)(u >> 16);
}

__device__ __forceinline__ void gload16(const void* g, void* l){
    __builtin_amdgcn_global_load_lds(
        (const __attribute__((address_space(1))) unsigned int*)g,
        (__attribute__((address_space(3))) unsigned int*)l, 16, 0, 0);
}

// compile-time fence: loads above CANNOT sink below (forces MLP, T14 pattern)
#define SBAR() __builtin_amdgcn_sched_barrier(0)

// ------- kernel 1: weight-decode (-> bt, polp) + latent f32->bf16 cast ------
__launch_bounds__(256)
__global__ void decode_all(const float* __restrict__ w,
                           const float* __restrict__ lat,
                           unsigned short* __restrict__ bt,
                           unsigned short* __restrict__ abf,
                           float* __restrict__ polp){
    __shared__ unsigned short tile[64][70];
    __shared__ float part[4];
    const int tid = threadIdx.x;
    const int bid = blockIdx.x;
    if (bid < 768){
        // ---- sigmoid-decode weight -> int_weights^T (bf16) ----
        const int k0 = (bid & 63) * 64;
        const int n0 = (bid >> 6) * 64;
        const int j     = tid & 63;
        const int ibase = (tid >> 6) * 16;
        float pol = 0.f;
        #pragma unroll
        for (int grp = 0; grp < 4; ++grp){
            // issue 8 16B loads (4 rows x 2); fence keeps them in flight
            float4 va[4][2];
            #pragma unroll
            for (int r = 0; r < 4; ++r){
                int i = ibase + grp*4 + r;
                const float4* src = (const float4*)(w + (size_t)(k0+i)*WCOLS
                                                      + (size_t)(n0+j)*8);
                va[r][0] = src[0];
                va[r][1] = src[1];
            }
            SBAR();
            #pragma unroll
            for (int r = 0; r < 4; ++r){
                float x[8] = {va[r][0].x, va[r][0].y, va[r][0].z, va[r][0].w,
                              va[r][1].x, va[r][1].y, va[r][1].z, va[r][1].w};
                float p[8];
                #pragma unroll
                for (int q = 0; q < 8; ++q){
                    p[q] = __builtin_amdgcn_rcpf(1.f + __expf(-x[q]));
                    pol += p[q] * (1.f - p[q]);
                }
                float iw = p[0] + 2.f*p[1] + 4.f*p[2] + 8.f*p[3]
                         + 16.f*p[4] + 32.f*p[5] + 64.f*p[6] - 128.f*p[7];
                tile[j][ibase + grp*4 + r] = f2bf(iw);
            }
        }
        #pragma unroll
        for (int off = 32; off; off >>= 1) pol += __shfl_down(pol, off);
        if ((tid & 63) == 0) part[tid >> 6] = pol;
        __syncthreads();
        const int nrow = tid >> 4;
        const int kb   = (tid & 15) * 4;
        #pragma unroll
        for (int q = 0; q < 4; ++q){
            int n = nrow + q*16;
            uint2 v;
            v.x = *(const unsigned int*)&tile[n][kb];
            v.y = *(const unsigned int*)&tile[n][kb+2];
            *(uint2*)(bt + (size_t)(n0+n)*IN_F + k0 + kb) = v;
        }
        if (tid == 0) polp[bid] = part[0]+part[1]+part[2]+part[3];
    } else {
        // ---- latent f32 -> bf16: 32 floats/thread, 8 loads held in flight --
        const int base = ((bid - 768) * 256 + tid) * 32;
        const float4* p = (const float4*)(lat + base);
        float4 v[8];
        #pragma unroll
        for (int i = 0; i < 8; ++i) v[i] = p[i];
        SBAR();
        #pragma unroll
        for (int h = 0; h < 4; ++h){
            ushort8 o;
            o[0]=f2bf(v[2*h].x);   o[1]=f2bf(v[2*h].y);
            o[2]=f2bf(v[2*h].z);   o[3]=f2bf(v[2*h].w);
            o[4]=f2bf(v[2*h+1].x); o[5]=f2bf(v[2*h+1].y);
            o[6]=f2bf(v[2*h+1].z); o[7]=f2bf(v[2*h+1].w);
            *(ushort8*)(abf + base + h*8) = o;
        }
    }
}

// ------- kernel 2: bf16 GEMM, 128x96 tile, K-split x2, m97 loop -------------
#define BM 128
#define BN 96
#define BK 64
#define NTH 32                     // K-steps per half (K=2048)
#define ABYTES (BM*BK*2)           // 16384
#define BBYTES (BN*BK*2)           // 12288
#define BUFB   (ABYTES+BBYTES)     // 28672

__launch_bounds__(256)
__global__ void gemm_pred(const unsigned short* __restrict__ abf,
                          const unsigned short* __restrict__ bt,
                          float* __restrict__ pred){
    __shared__ __align__(16) char smem[2*BUFB];   // 56 KB -> 2 blocks/CU
    const int tid = threadIdx.x;
    const int w   = tid >> 6;
    const int l   = tid & 63;
    const int s   = l & 15, g = l >> 4;
    const int wr  = w >> 1, wc = w & 1;    // 2x2 waves, wave tile 64x48
    const int bid  = blockIdx.x;
    const int half = bid >> 8;             // K-half
    const int rem  = bid & 255;
    const int m0   = (rem >> 3) * BM;
    const int n0   = (rem & 7)  * BN;      // bid&7 == n-panel -> XCD-stable
    const int kb   = half * (NTH*BK);

    f32x4 accv[4][3];
    #pragma unroll
    for (int m = 0; m < 4; ++m)
        #pragma unroll
        for (int n = 0; n < 3; ++n)
            accv[m][n] = (f32x4){0.f,0.f,0.f,0.f};

    const int c8  = tid & 7;
    const int r0  = tid >> 3;                    // 0..31; (r0+32i)&7 == r0&7
    const int scw = ((c8 ^ (r0 & 7)) << 3);
    const unsigned short* aS = abf + (size_t)(m0 + r0) * IN_F + kb + scw;
    const unsigned short* bS = bt  + (size_t)(n0 + r0) * IN_F + kb + scw;

    #define STAGE(kt, base) do {                                           \
        const int _ko = (kt) * BK;                                         \
        char* _ad = (base) + tid*16;                                       \
        char* _bd = (base) + ABYTES + tid*16;                              \
        _Pragma("unroll")                                                  \
        for (int _i = 0; _i < 4; ++_i)                                     \
            gload16(aS + (size_t)_i*32*IN_F + _ko, _ad + _i*4096);         \
        _Pragma("unroll")                                                  \
        for (int _i = 0; _i < 3; ++_i)                                     \
            gload16(bS + (size_t)_i*32*IN_F + _ko, _bd + _i*4096);         \
    } while (0)

    #define COMPUTE(base) do {                                             \
        char* _Ab = (base);                                                \
        char* _Bb = (base) + ABYTES;                                       \
        _Pragma("unroll")                                                  \
        for (int _kk = 0; _kk < 2; ++_kk){                                 \
            bf16x8 _af[4], _bf[3];                                         \
            _Pragma("unroll")                                              \
            for (int _m = 0; _m < 4; ++_m){                                \
                int _r  = wr*64 + _m*16 + s;                               \
                int _ch = _r*8 + ((_kk*4 + g) ^ (_r & 7));                 \
                _af[_m] = *(const bf16x8*)(_Ab + _ch*16);                  \
            }                                                              \
            _Pragma("unroll")                                              \
            for (int _n = 0; _n < 3; ++_n){                                \
                int _r  = wc*48 + _n*16 + s;                               \
                int _ch = _r*8 + ((_kk*4 + g) ^ (_r & 7));                 \
                _bf[_n] = *(const bf16x8*)(_Bb + _ch*16);                  \
            }                                                              \
            __builtin_amdgcn_s_setprio(1);                                 \
            _Pragma("unroll")                                              \
            for (int _m = 0; _m < 4; ++_m)                                 \
                _Pragma("unroll")                                          \
                for (int _n = 0; _n < 3; ++_n)                             \
                    accv[_m][_n] = __builtin_amdgcn_mfma_f32_16x16x32_bf16(\
                        _af[_m], _bf[_n], accv[_m][_n], 0, 0, 0);          \
            __builtin_amdgcn_s_setprio(0);                                 \
        }                                                                  \
    } while (0)

    char* b0 = smem;
    char* b1 = smem + BUFB;
    STAGE(0, b0);
    __syncthreads();
    for (int t = 0; t < NTH; ++t){
        if (t + 1 < NTH) STAGE(t + 1, (t & 1) ? b0 : b1);
        COMPUTE((t & 1) ? b1 : b0);
        __syncthreads();
    }

    float* slab = pred + (size_t)half * PREDN;
    #pragma unroll
    for (int m = 0; m < 4; ++m){
        int rbase = m0 + wr*64 + m*16 + g*4;
        #pragma unroll
        for (int n = 0; n < 3; ++n){
            int col = n0 + wc*48 + n*16 + s;
            #pragma unroll
            for (int jj = 0; jj < 4; ++jj)
                slab[(size_t)(rbase+jj)*OUT_F + col] = accv[m][n][jj];
        }
    }
}

// ------- kernel 3: loss pass: pred slabs + raw ts decode -> lossp -----------
__launch_bounds__(256)
__global__ void loss_pass(const float* __restrict__ pred,
                          const float* __restrict__ ts,
                          float* __restrict__ lossp){
    __shared__ float part[4];
    const int tid = threadIdx.x;
    const int e0  = (blockIdx.x * 256 + tid) * 4;
    // issue: 2 pred float4 + 8 ts float4; fence keeps all 10 in flight
    const float4 p0 = *(const float4*)(pred + e0);
    const float4 p1 = *(const float4*)(pred + (size_t)PREDN + e0);
    float4 t[8];
    const float4* r = (const float4*)(ts + (size_t)e0 * 8);
    #pragma unroll
    for (int i = 0; i < 8; ++i) t[i] = r[i];
    SBAR();
    float local = 0.f;
    #pragma unroll
    for (int q = 0; q < 4; ++q){
        float4 x = t[2*q], y = t[2*q+1];
        float is = x.x + 2.f*x.y + 4.f*x.z + 8.f*x.w
                 + 16.f*y.x + 32.f*y.y + 64.f*y.z - 128.f*y.w;
        float pv = (q==0) ? (p0.x+p1.x) : (q==1) ? (p0.y+p1.y)
                 : (q==2) ? (p0.z+p1.z) : (p0.w+p1.w);
        float d = pv - is;
        local += d*d;
    }
    #pragma unroll
    for (int off = 32; off; off >>= 1) local += __shfl_down(local, off);
    if ((tid & 63) == 0) part[tid >> 6] = local;
    __syncthreads();
    if (tid == 0) lossp[blockIdx.x] = part[0]+part[1]+part[2]+part[3];
}

// ------- kernel 4: finalize -------------------------------------------------
__launch_bounds__(256)
__global__ void finalize(const float* __restrict__ lossp,
                         const float* __restrict__ polp,
                         float* __restrict__ out){
    __shared__ float sm[2][4];
    const int tid = threadIdx.x;
    float a = 0.f, b = 0.f;
    for (int i = tid; i < 3072; i += 256) a += lossp[i];
    for (int i = tid; i < 768;  i += 256) b += polp[i];
    #pragma unroll
    for (int off = 32; off; off >>= 1){
        a += __shfl_down(a, off);
        b += __shfl_down(b, off);
    }
    if ((tid & 63) == 0){ sm[0][tid >> 6] = a; sm[1][tid >> 6] = b; }
    __syncthreads();
    if (tid == 0){
        float sa = sm[0][0]+sm[0][1]+sm[0][2]+sm[0][3];
        float sb = sm[1][0]+sm[1][1]+sm[1][2]+sm[1][3];
        out[0] = sa * (1.0f / ((float)BATCH * (float)OUT_F * 128.0f));
        out[1] = sb * (1.0f / ((float)IN_F * (float)WCOLS));
    }
}

extern "C" void kernel_launch(void* const* d_in, const int* in_sizes, int n_in,
                              void* d_out, int out_size, void* d_ws, size_t ws_size,
                              hipStream_t stream){
    const float* latent   = (const float*)d_in[0];
    const float* true_sum = (const float*)d_in[1];
    const float* weight   = (const float*)d_in[2];
    char* ws = (char*)d_ws;
    float* lossp = (float*)ws;                                  // 12 KB
    float* polp  = (float*)(ws + 32768);                        // 3 KB
    unsigned short* bt  = (unsigned short*)(ws + 65536);        // 6 MB
    unsigned short* abf = (unsigned short*)(ws + 65536 + 6291456);      // 32 MB
    float* pred = (float*)(ws + 65536 + 6291456 + 33554432);    // 2x12.6 MB
    float* out = (float*)d_out;

    decode_all<<<768 + 2048, 256, 0, stream>>>(weight, latent, bt, abf, polp);
    gemm_pred<<<512, 256, 0, stream>>>(abf, bt, pred);
    loss_pass<<<PREDN/1024, 256, 0, stream>>>(pred, true_sum, lossp);
    finalize<<<1, 256, 0, stream>>>(lossp, polp, out);
}

// Round 10
// 107.100 us; speedup vs baseline: 1.0407x; 1.0407x over previous
//
#include <hip/hip_runtime.h>
#include <stdint.h>

#define IN_F   4096
#define OUT_F  768
#define NB     8
#define BATCH  4096
#define WCOLS  (OUT_F*NB)   // 6144
#define PREDN  (BATCH*OUT_F) // 3145728

typedef short  bf16x8  __attribute__((ext_vector_type(8)));
typedef float  f32x4   __attribute__((ext_vector_type(4)));
typedef unsigned short ushort4v __attribute__((ext_vector_type(4)));

__device__ __forceinline__ unsigned short f2bf(float f){
    union { float f; uint32_t u; } v; v.f = f;
    uint32_t u = v.u;
    u += 0x7FFFu + ((u >> 16) & 1u);   // round-to-nearest-even
    return (unsigned short)(u >> 16);
}

__device__ __forceinline__ void gload16(const void* g, void* l){
    __builtin_amdgcn_global_load_lds(
        (const __attribute__((address_space(1))) unsigned int*)g,
        (__attribute__((address_space(3))) unsigned int*)l, 16, 0, 0);
}

#define SBAR() __builtin_amdgcn_sched_barrier(0)

// ------- kernel 1: weight-decode (-> bt, polp) + latent f32->bf16 cast ------
// All global reads lane-contiguous (16B/lane, 1KB/wave/instruction).
__launch_bounds__(256)
__global__ void decode_all(const float* __restrict__ w,
                           const float* __restrict__ lat,
                           unsigned short* __restrict__ bt,
                           unsigned short* __restrict__ abf,
                           float* __restrict__ polp){
    __shared__ unsigned short tile[64][70];
    __shared__ float part[4];
    const int tid = threadIdx.x;
    const int bid = blockIdx.x;
    if (bid < 768){
        // ---- sigmoid-decode weight -> int_weights^T (bf16) ----
        // Per k-row: 512 floats = 128 f4; lane l takes f4[l], f4[l+64]
        // (coalesced); parity dot + shfl_xor(1) assembles each column's 8 bits.
        const int k0 = (bid & 63) * 64;
        const int n0 = (bid >> 6) * 64;
        const int wv = tid >> 6;           // wave 0..3 -> rows wv*16..+15
        const int l  = tid & 63;
        const int par = l & 1;
        const float c0 = par ? 16.f : 1.f;
        const float c1 = par ? 32.f : 2.f;
        const float c2 = par ? 64.f : 4.f;
        const float c3 = par ? -128.f : 8.f;
        const f32x4* wf4 = (const f32x4*)w;
        float pol = 0.f;
        #pragma unroll
        for (int rq = 0; rq < 4; ++rq){
            f32x4 va[4][2];
            #pragma unroll
            for (int rr = 0; rr < 4; ++rr){
                int i = wv*16 + rq*4 + rr;
                size_t rb = (size_t)(k0 + i) * 1536 + n0 * 2;
                va[rr][0] = wf4[rb + l];
                va[rr][1] = wf4[rb + 64 + l];
            }
            SBAR();
            #pragma unroll
            for (int rr = 0; rr < 4; ++rr){
                int i = wv*16 + rq*4 + rr;
                #pragma unroll
                for (int h = 0; h < 2; ++h){
                    f32x4 v = va[rr][h];
                    float s0 = __builtin_amdgcn_rcpf(1.f + __expf(-v[0]));
                    float s1 = __builtin_amdgcn_rcpf(1.f + __expf(-v[1]));
                    float s2 = __builtin_amdgcn_rcpf(1.f + __expf(-v[2]));
                    float s3 = __builtin_amdgcn_rcpf(1.f + __expf(-v[3]));
                    pol += s0*(1.f-s0) + s1*(1.f-s1) + s2*(1.f-s2) + s3*(1.f-s3);
                    float d = s0*c0 + s1*c1 + s2*c2 + s3*c3;
                    float iw = d + __shfl_xor(d, 1);
                    tile[h*32 + (l >> 1)][i] = f2bf(iw);   // pair-dup write, benign
                }
            }
        }
        #pragma unroll
        for (int off = 32; off; off >>= 1) pol += __shfl_down(pol, off);
        if ((tid & 63) == 0) part[tid >> 6] = pol;
        __syncthreads();
        const int nrow = tid >> 4;
        const int kb   = (tid & 15) * 4;
        #pragma unroll
        for (int q = 0; q < 4; ++q){
            int n = nrow + q*16;
            uint2 v;
            v.x = *(const unsigned int*)&tile[n][kb];
            v.y = *(const unsigned int*)&tile[n][kb+2];
            *(uint2*)(bt + (size_t)(n0+n)*IN_F + k0 + kb) = v;
        }
        if (tid == 0) polp[bid] = part[0]+part[1]+part[2]+part[3];
    } else {
        // ---- latent f32 -> bf16: strided-by-256 f4 loads, coalesced --------
        const int base = (bid - 768) * 8192;     // floats
        const f32x4* p = (const f32x4*)(lat + base);
        ushort4v* o = (ushort4v*)(abf + base);
        f32x4 v[8];
        #pragma unroll
        for (int i = 0; i < 8; ++i) v[i] = p[tid + i*256];
        SBAR();
        #pragma unroll
        for (int i = 0; i < 8; ++i){
            ushort4v u;
            u[0]=f2bf(v[i][0]); u[1]=f2bf(v[i][1]);
            u[2]=f2bf(v[i][2]); u[3]=f2bf(v[i][3]);
            o[tid + i*256] = u;
        }
    }
}

// ------- kernel 2: bf16 GEMM, 128x96 tile, K-split x2, m97 loop -------------
#define BM 128
#define BN 96
#define BK 64
#define NTH 32                     // K-steps per half (K=2048)
#define ABYTES (BM*BK*2)           // 16384
#define BBYTES (BN*BK*2)           // 12288
#define BUFB   (ABYTES+BBYTES)     // 28672

__launch_bounds__(256)
__global__ void gemm_pred(const unsigned short* __restrict__ abf,
                          const unsigned short* __restrict__ bt,
                          float* __restrict__ pred){
    __shared__ __align__(16) char smem[2*BUFB];   // 56 KB -> 2 blocks/CU
    const int tid = threadIdx.x;
    const int w   = tid >> 6;
    const int l   = tid & 63;
    const int s   = l & 15, g = l >> 4;
    const int wr  = w >> 1, wc = w & 1;    // 2x2 waves, wave tile 64x48
    const int bid  = blockIdx.x;
    const int half = bid >> 8;             // K-half
    const int rem  = bid & 255;
    const int m0   = (rem >> 3) * BM;
    const int n0   = (rem & 7)  * BN;      // bid&7 == n-panel -> XCD-stable
    const int kb   = half * (NTH*BK);

    f32x4 accv[4][3];
    #pragma unroll
    for (int m = 0; m < 4; ++m)
        #pragma unroll
        for (int n = 0; n < 3; ++n)
            accv[m][n] = (f32x4){0.f,0.f,0.f,0.f};

    const int c8  = tid & 7;
    const int r0  = tid >> 3;                    // 0..31; (r0+32i)&7 == r0&7
    const int scw = ((c8 ^ (r0 & 7)) << 3);
    const unsigned short* aS = abf + (size_t)(m0 + r0) * IN_F + kb + scw;
    const unsigned short* bS = bt  + (size_t)(n0 + r0) * IN_F + kb + scw;

    #define STAGE(kt, base) do {                                           \
        const int _ko = (kt) * BK;                                         \
        char* _ad = (base) + tid*16;                                       \
        char* _bd = (base) + ABYTES + tid*16;                              \
        _Pragma("unroll")                                                  \
        for (int _i = 0; _i < 4; ++_i)                                     \
            gload16(aS + (size_t)_i*32*IN_F + _ko, _ad + _i*4096);         \
        _Pragma("unroll")                                                  \
        for (int _i = 0; _i < 3; ++_i)                                     \
            gload16(bS + (size_t)_i*32*IN_F + _ko, _bd + _i*4096);         \
    } while (0)

    #define COMPUTE(base) do {                                             \
        char* _Ab = (base);                                                \
        char* _Bb = (base) + ABYTES;                                       \
        _Pragma("unroll")                                                  \
        for (int _kk = 0; _kk < 2; ++_kk){                                 \
            bf16x8 _af[4], _bf[3];                                         \
            _Pragma("unroll")                                              \
            for (int _m = 0; _m < 4; ++_m){                                \
                int _r  = wr*64 + _m*16 + s;                               \
                int _ch = _r*8 + ((_kk*4 + g) ^ (_r & 7));                 \
                _af[_m] = *(const bf16x8*)(_Ab + _ch*16);                  \
            }                                                              \
            _Pragma("unroll")                                              \
            for (int _n = 0; _n < 3; ++_n){                                \
                int _r  = wc*48 + _n*16 + s;                               \
                int _ch = _r*8 + ((_kk*4 + g) ^ (_r & 7));                 \
                _bf[_n] = *(const bf16x8*)(_Bb + _ch*16);                  \
            }                                                              \
            __builtin_amdgcn_s_setprio(1);                                 \
            _Pragma("unroll")                                              \
            for (int _m = 0; _m < 4; ++_m)                                 \
                _Pragma("unroll")                                          \
                for (int _n = 0; _n < 3; ++_n)                             \
                    accv[_m][_n] = __builtin_amdgcn_mfma_f32_16x16x32_bf16(\
                        _af[_m], _bf[_n], accv[_m][_n], 0, 0, 0);          \
            __builtin_amdgcn_s_setprio(0);                                 \
        }                                                                  \
    } while (0)

    char* b0 = smem;
    char* b1 = smem + BUFB;
    STAGE(0, b0);
    __syncthreads();
    for (int t = 0; t < NTH; ++t){
        if (t + 1 < NTH) STAGE(t + 1, (t & 1) ? b0 : b1);
        COMPUTE((t & 1) ? b1 : b0);
        __syncthreads();
    }

    float* slab = pred + (size_t)half * PREDN;
    #pragma unroll
    for (int m = 0; m < 4; ++m){
        int rbase = m0 + wr*64 + m*16 + g*4;
        #pragma unroll
        for (int n = 0; n < 3; ++n){
            int col = n0 + wc*48 + n*16 + s;
            #pragma unroll
            for (int jj = 0; jj < 4; ++jj)
                slab[(size_t)(rbase+jj)*OUT_F + col] = accv[m][n][jj];
        }
    }
}

// ------- kernel 3: loss pass, coalesced ts stream ---------------------------
// Lane-contiguous ts f4 loads; parity dot + shfl_xor(1) pairwise combine.
// Each element lands in both lanes of a pair -> 0.5x scale.
__launch_bounds__(256)
__global__ void loss_pass(const float* __restrict__ pred,
                          const float* __restrict__ ts,
                          float* __restrict__ lossp){
    __shared__ float part[4];
    const int tid = threadIdx.x;
    const int blk = blockIdx.x;
    const f32x4* tsp = (const f32x4*)(ts + (size_t)blk * 8192);
    const int par = tid & 1;
    const float c0 = par ? 16.f : 1.f;
    const float c1 = par ? 32.f : 2.f;
    const float c2 = par ? 64.f : 4.f;
    const float c3 = par ? -128.f : 8.f;

    f32x4 v[8];
    float pr0[8], pr1[8];
    #pragma unroll
    for (int i = 0; i < 8; ++i) v[i] = tsp[tid + i*256];
    #pragma unroll
    for (int i = 0; i < 8; ++i){
        int E = blk*1024 + (tid >> 1) + i*128;
        pr0[i] = pred[E];
        pr1[i] = pred[(size_t)PREDN + E];
    }
    SBAR();
    float local = 0.f;
    #pragma unroll
    for (int i = 0; i < 8; ++i){
        float d = v[i][0]*c0 + v[i][1]*c1 + v[i][2]*c2 + v[i][3]*c3;
        float is = d + __shfl_xor(d, 1);
        float diff = (pr0[i] + pr1[i]) - is;
        local += diff*diff;
    }
    local *= 0.5f;   // pair duplication
    #pragma unroll
    for (int off = 32; off; off >>= 1) local += __shfl_down(local, off);
    if ((tid & 63) == 0) part[tid >> 6] = local;
    __syncthreads();
    if (tid == 0) lossp[blk] = part[0]+part[1]+part[2]+part[3];
}

// ------- kernel 4: finalize -------------------------------------------------
__launch_bounds__(256)
__global__ void finalize(const float* __restrict__ lossp,
                         const float* __restrict__ polp,
                         float* __restrict__ out){
    __shared__ float sm[2][4];
    const int tid = threadIdx.x;
    float a = 0.f, b = 0.f;
    for (int i = tid; i < 3072; i += 256) a += lossp[i];
    for (int i = tid; i < 768;  i += 256) b += polp[i];
    #pragma unroll
    for (int off = 32; off; off >>= 1){
        a += __shfl_down(a, off);
        b += __shfl_down(b, off);
    }
    if ((tid & 63) == 0){ sm[0][tid >> 6] = a; sm[1][tid >> 6] = b; }
    __syncthreads();
    if (tid == 0){
        float sa = sm[0][0]+sm[0][1]+sm[0][2]+sm[0][3];
        float sb = sm[1][0]+sm[1][1]+sm[1][2]+sm[1][3];
        out[0] = sa * (1.0f / ((float)BATCH * (float)OUT_F * 128.0f));
        out[1] = sb * (1.0f / ((float)IN_F * (float)WCOLS));
    }
}

extern "C" void kernel_launch(void* const* d_in, const int* in_sizes, int n_in,
                              void* d_out, int out_size, void* d_ws, size_t ws_size,
                              hipStream_t stream){
    const float* latent   = (const float*)d_in[0];
    const float* true_sum = (const float*)d_in[1];
    const float* weight   = (const float*)d_in[2];
    char* ws = (char*)d_ws;
    float* lossp = (float*)ws;                                  // 12 KB
    float* polp  = (float*)(ws + 32768);                        // 3 KB
    unsigned short* bt  = (unsigned short*)(ws + 65536);        // 6 MB
    unsigned short* abf = (unsigned short*)(ws + 65536 + 6291456);      // 32 MB
    float* pred = (float*)(ws + 65536 + 6291456 + 33554432);    // 2x12.6 MB
    float* out = (float*)d_out;

    decode_all<<<768 + 2048, 256, 0, stream>>>(weight, latent, bt, abf, polp);
    gemm_pred<<<512, 256, 0, stream>>>(abf, bt, pred);
    loss_pass<<<PREDN/1024, 256, 0, stream>>>(pred, true_sum, lossp);
    finalize<<<1, 256, 0, stream>>>(lossp, polp, out);
}